// Round 7
// baseline (276.481 us; speedup 1.0000x reference)
//
#include <hip/hip_runtime.h>

// HyperNet fused forward, v10.
//   logits = h1 @ (enc_w2 @ comb_top) + h2 @ (pol_w3 @ comb_bot) + (pol_b3 @ comb_bot + comb_b)
//   h1 = relu(enc @ enc_w1) [N,64],  h2 = relu(relu(mean@pol_w1+b1)@pol_w2+b2) [N,32]
//
// R6 post-mortem: v9's s_load conversion verified (SGPR 64, no LDS) but dur unchanged
//   (75us, VALUBusy 47%) at 3x the occupancy -> shared limit of v4/v9 is the per-CU L2
//   read path: every block re-reads the full 397KB fused (v9: 3.2MB/CU ~ 42GB/s/CU
//   effective). VGPR=36 also shows the compiler collapsed the w-prefetch (serialized
//   L2 round-trip per k4).
// v10: logits blocks cover 32 rows (512 blocks, acc[32] f4 = 128 VGPR, lb(256,2)):
//   4x less fused traffic per CU (0.8MB), and each w-quad feeds 512 FMAs -> L2 latency
//   hidden by ILP instead of TLP. h via s_load (proven), w plain load (compiler schedules).

#define N_CLIENTS 16384
#define P 1024
#define IN_DIM 512
#define SPAD 36   // LDS row stride for A tiles

#define FMA4(acc, a, w0, w1, w2, w3)                                  \
  acc.x = fmaf(a.x, w0.x, acc.x); acc.y = fmaf(a.x, w0.y, acc.y);     \
  acc.z = fmaf(a.x, w0.z, acc.z); acc.w = fmaf(a.x, w0.w, acc.w);     \
  acc.x = fmaf(a.y, w1.x, acc.x); acc.y = fmaf(a.y, w1.y, acc.y);     \
  acc.z = fmaf(a.y, w1.z, acc.z); acc.w = fmaf(a.y, w1.w, acc.w);     \
  acc.x = fmaf(a.z, w2.x, acc.x); acc.y = fmaf(a.z, w2.y, acc.y);     \
  acc.z = fmaf(a.z, w2.z, acc.z); acc.w = fmaf(a.z, w2.w, acc.w);     \
  acc.x = fmaf(a.w, w3.x, acc.x); acc.y = fmaf(a.w, w3.y, acc.y);     \
  acc.z = fmaf(a.w, w3.z, acc.z); acc.w = fmaf(a.w, w3.w, acc.w);

// ---------------------------------------------------------------------------
// stage1 (v4-proven): blocks [0,512) h1 | [512,768) h2 | [768,1600) precompute
// ---------------------------------------------------------------------------
__global__ __launch_bounds__(256) void stage1(
    const float* __restrict__ encoding,  // [N][512]
    const float* __restrict__ mean,      // [N][1024]
    const float* __restrict__ enc_w1,    // [512][64]
    const float* __restrict__ pol_w1,    // [1024][32]
    const float* __restrict__ pol_b1,    // [32]
    const float* __restrict__ pol_w2,    // [32][32]
    const float* __restrict__ pol_b2,    // [32]
    const float* __restrict__ enc_w2,    // [64][1024]
    const float* __restrict__ pol_w3,    // [32][1024]
    const float* __restrict__ pol_b3,    // [1024]
    const float* __restrict__ comb_w,    // [2048][1024]
    const float* __restrict__ comb_b,    // [1024]
    float* __restrict__ h1h2,            // [N][96]
    float* __restrict__ fused)           // [97][1024] (pre-zeroed)
{
    __shared__ __attribute__((aligned(16))) float smem[64 * SPAD + 32 * 32]; // 13.3 KB
    const int t = threadIdx.x;
    const int bid = blockIdx.x;

    if (bid < 512) {
        // ---- h1: 32 rows x 64 cols, K=512 in 16 tiles of 32, reg-prefetch staging.
        float* sA = smem;                 // [32][SPAD]
        float* sW = smem + 32 * SPAD;     // [32][64]
        const long r0 = (long)bid * 32;
        const int tr = t & 15, rr = t >> 4;
        const int c0 = tr * 4;
        const int arow = t >> 3, aseg = t & 7;
        const float* aSrc = encoding + (r0 + arow) * IN_DIM + aseg * 4;

        float4 aR  = *(const float4*)(aSrc);
        float4 wR0 = *(const float4*)(enc_w1 + t * 4);
        float4 wR1 = *(const float4*)(enc_w1 + (256 + t) * 4);
        float4 acc0 = {0.f,0.f,0.f,0.f}, acc1 = {0.f,0.f,0.f,0.f};

        for (int kt = 0; kt < 16; ++kt) {
            __syncthreads();
            *(float4*)(sA + arow * SPAD + aseg * 4) = aR;
            *(float4*)(sW + t * 4) = wR0;
            *(float4*)(sW + (256 + t) * 4) = wR1;
            __syncthreads();
            if (kt < 15) {   // prefetch next tile while computing this one
                aR  = *(const float4*)(aSrc + (kt + 1) * 32);
                wR0 = *(const float4*)(enc_w1 + (kt + 1) * 2048 + t * 4);
                wR1 = *(const float4*)(enc_w1 + (kt + 1) * 2048 + (256 + t) * 4);
            }
            #pragma unroll
            for (int k4 = 0; k4 < 8; ++k4) {
                const float4 a0 = *(const float4*)(sA + (rr * 2 + 0) * SPAD + k4 * 4);
                const float4 a1 = *(const float4*)(sA + (rr * 2 + 1) * SPAD + k4 * 4);
                const float4 w0 = *(const float4*)(sW + (k4 * 4 + 0) * 64 + c0);
                const float4 w1 = *(const float4*)(sW + (k4 * 4 + 1) * 64 + c0);
                const float4 w2 = *(const float4*)(sW + (k4 * 4 + 2) * 64 + c0);
                const float4 w3 = *(const float4*)(sW + (k4 * 4 + 3) * 64 + c0);
                FMA4(acc0, a0, w0, w1, w2, w3);
                FMA4(acc1, a1, w0, w1, w2, w3);
            }
        }
        float4 o0, o1;
        o0.x = fmaxf(acc0.x, 0.f); o0.y = fmaxf(acc0.y, 0.f);
        o0.z = fmaxf(acc0.z, 0.f); o0.w = fmaxf(acc0.w, 0.f);
        o1.x = fmaxf(acc1.x, 0.f); o1.y = fmaxf(acc1.y, 0.f);
        o1.z = fmaxf(acc1.z, 0.f); o1.w = fmaxf(acc1.w, 0.f);
        *(float4*)(h1h2 + (r0 + rr * 2 + 0) * 96 + c0) = o0;
        *(float4*)(h1h2 + (r0 + rr * 2 + 1) * 96 + c0) = o1;
    } else if (bid < 768) {
        // ---- h2: 64 rows x 32 cols, K=1024 in 32 tiles of 32, then layer2 in-block.
        float* sA = smem;                 // [64][SPAD]
        float* sW = smem + 64 * SPAD;     // [32][32]
        const long r0 = (long)(bid - 512) * 64;
        const int tr = t & 7, rr = t >> 3;
        const int c0 = tr * 4;
        const int arow0 = t >> 3,        aseg = t & 7;
        const int arow1 = 32 + (t >> 3);
        const float* aSrc0 = mean + (r0 + arow0) * P + aseg * 4;
        const float* aSrc1 = mean + (r0 + arow1) * P + aseg * 4;

        float4 aR0 = *(const float4*)(aSrc0);
        float4 aR1 = *(const float4*)(aSrc1);
        float4 wR  = *(const float4*)(pol_w1 + t * 4);
        float4 acc0 = {0.f,0.f,0.f,0.f}, acc1 = {0.f,0.f,0.f,0.f};

        for (int kt = 0; kt < 32; ++kt) {
            __syncthreads();
            *(float4*)(sA + arow0 * SPAD + aseg * 4) = aR0;
            *(float4*)(sA + arow1 * SPAD + aseg * 4) = aR1;
            *(float4*)(sW + t * 4) = wR;
            __syncthreads();
            if (kt < 31) {
                aR0 = *(const float4*)(aSrc0 + (kt + 1) * 32);
                aR1 = *(const float4*)(aSrc1 + (kt + 1) * 32);
                wR  = *(const float4*)(pol_w1 + (kt + 1) * 1024 + t * 4);
            }
            #pragma unroll
            for (int k4 = 0; k4 < 8; ++k4) {
                const float4 a0 = *(const float4*)(sA + (rr * 2 + 0) * SPAD + k4 * 4);
                const float4 a1 = *(const float4*)(sA + (rr * 2 + 1) * SPAD + k4 * 4);
                const float4 w0 = *(const float4*)(sW + (k4 * 4 + 0) * 32 + c0);
                const float4 w1 = *(const float4*)(sW + (k4 * 4 + 1) * 32 + c0);
                const float4 w2 = *(const float4*)(sW + (k4 * 4 + 2) * 32 + c0);
                const float4 w3 = *(const float4*)(sW + (k4 * 4 + 3) * 32 + c0);
                FMA4(acc0, a0, w0, w1, w2, w3);
                FMA4(acc1, a1, w0, w1, w2, w3);
            }
        }
        // t1 = relu(acc+b1) -> sA; stage pol_w2 -> sW
        __syncthreads();
        {
            const float4 b1 = *(const float4*)(pol_b1 + c0);
            float4 t10, t11;
            t10.x = fmaxf(acc0.x + b1.x, 0.f); t10.y = fmaxf(acc0.y + b1.y, 0.f);
            t10.z = fmaxf(acc0.z + b1.z, 0.f); t10.w = fmaxf(acc0.w + b1.w, 0.f);
            t11.x = fmaxf(acc1.x + b1.x, 0.f); t11.y = fmaxf(acc1.y + b1.y, 0.f);
            t11.z = fmaxf(acc1.z + b1.z, 0.f); t11.w = fmaxf(acc1.w + b1.w, 0.f);
            *(float4*)(sA + (rr * 2 + 0) * SPAD + c0) = t10;
            *(float4*)(sA + (rr * 2 + 1) * SPAD + c0) = t11;
        }
        *(float4*)(sW + t * 4) = *(const float4*)(pol_w2 + t * 4);
        __syncthreads();

        float4 d0 = {0.f,0.f,0.f,0.f}, d1 = {0.f,0.f,0.f,0.f};
        #pragma unroll
        for (int k4 = 0; k4 < 8; ++k4) {
            const float4 a0 = *(const float4*)(sA + (rr * 2 + 0) * SPAD + k4 * 4);
            const float4 a1 = *(const float4*)(sA + (rr * 2 + 1) * SPAD + k4 * 4);
            const float4 w0 = *(const float4*)(sW + (k4 * 4 + 0) * 32 + c0);
            const float4 w1 = *(const float4*)(sW + (k4 * 4 + 1) * 32 + c0);
            const float4 w2 = *(const float4*)(sW + (k4 * 4 + 2) * 32 + c0);
            const float4 w3 = *(const float4*)(sW + (k4 * 4 + 3) * 32 + c0);
            FMA4(d0, a0, w0, w1, w2, w3);
            FMA4(d1, a1, w0, w1, w2, w3);
        }
        const float4 b2 = *(const float4*)(pol_b2 + c0);
        float4 o0, o1;
        o0.x = fmaxf(d0.x + b2.x, 0.f); o0.y = fmaxf(d0.y + b2.y, 0.f);
        o0.z = fmaxf(d0.z + b2.z, 0.f); o0.w = fmaxf(d0.w + b2.w, 0.f);
        o1.x = fmaxf(d1.x + b2.x, 0.f); o1.y = fmaxf(d1.y + b2.y, 0.f);
        o1.z = fmaxf(d1.z + b2.z, 0.f); o1.w = fmaxf(d1.w + b2.w, 0.f);
        *(float4*)(h1h2 + (r0 + rr * 2 + 0) * 96 + 64 + c0) = o0;
        *(float4*)(h1h2 + (r0 + rr * 2 + 1) * 96 + 64 + c0) = o1;
    } else {
        // ---- fused-weight precompute: pid -> (j-chunk, row-group, k-chunk of 64)
        const int pid = bid - 768;          // [0, 832)
        const int jc = pid & 3;
        const int rest = pid >> 2;          // [0, 208)
        const int by = rest % 13;
        const int kz = rest / 13;           // [0, 16)
        const int j = jc * 256 + t;

        const float* wsrc; int nr, kbase, outbase;
        if (by < 8)       { wsrc = enc_w2 + by * 8 * 1024;        nr = 8; kbase = 0;    outbase = by * 8; }
        else if (by < 12) { wsrc = pol_w3 + (by - 8) * 8 * 1024;  nr = 8; kbase = 1024; outbase = 64 + (by - 8) * 8; }
        else              { wsrc = pol_b3;                        nr = 1; kbase = 1024; outbase = 96; }

        float* s_w = smem;   // [8][64]
        for (int i = t; i < nr * 64; i += 256)
            s_w[i] = wsrc[(i >> 6) * 1024 + kz * 64 + (i & 63)];
        __syncthreads();

        float acc[8];
        #pragma unroll
        for (int r = 0; r < 8; ++r) acc[r] = 0.f;
        const float* cw = comb_w + ((size_t)kbase + kz * 64) * 1024 + j;
        #pragma unroll 4
        for (int k = 0; k < 64; ++k) {
            const float c = cw[(size_t)k * 1024];
            #pragma unroll
            for (int r = 0; r < 8; ++r) acc[r] = fmaf(s_w[r * 64 + k], c, acc[r]);
        }
        if (by == 12) {
            atomicAdd(&fused[96 * 1024 + j], acc[0] + (kz == 0 ? comb_b[j] : 0.f));
        } else {
            #pragma unroll
            for (int r = 0; r < 8; ++r) atomicAdd(&fused[(outbase + r) * 1024 + j], acc[r]);
        }
    }
}

// ---------------------------------------------------------------------------
// logits + epilogue, 32-row ILP edition. Block = 32 rows x 1024 cols (512
// blocks); thread = 32 rows x 4 contiguous cols, acc[32] float4 (128 VGPR,
// launch_bounds(256,2) -> 2 blocks/CU). Each w-quad load feeds 512 FMAs so
// L2 latency hides under ILP; per-CU fused traffic is 0.8MB (4x less than v9).
// h via wave-uniform s_load_dwordx4 (v9-proven). No LDS in the GEMM.
// ---------------------------------------------------------------------------
__global__ __launch_bounds__(256, 2) void logits_ep(
    const float* __restrict__ h1h2,    // [N][96]
    const float* __restrict__ fused,   // [97][1024]
    const float* __restrict__ eps,     // [N][1024]
    float* __restrict__ out_sample,    // [N][1024]
    float* __restrict__ out_logprob,   // [N]
    float* __restrict__ out_entropy)   // [N]
{
    __shared__ float s_red[32][4];
    const int t = threadIdx.x;
    const long r0 = (long)blockIdx.x * 32;
    const float* hb = h1h2 + r0 * 96;   // block-uniform base -> scalar loads

    const int j0 = t * 4;
    const float* fj = fused + j0;

    float4 acc[32];
    {
        const float4 b = *(const float4*)(fj + 96 * 1024);
        #pragma unroll
        for (int r = 0; r < 32; ++r) acc[r] = b;
    }

    for (int k4 = 0; k4 < 24; ++k4) {
        const float* fk = fj + (size_t)(k4 * 4) * 1024;
        const float4 w0 = *(const float4*)(fk);
        const float4 w1 = *(const float4*)(fk + 1024);
        const float4 w2 = *(const float4*)(fk + 2048);
        const float4 w3 = *(const float4*)(fk + 3072);
        const float* hk = hb + k4 * 4;
        #pragma unroll
        for (int r = 0; r < 32; ++r) {
            // uniform address -> s_load_dwordx4; immediate offset r*384B
            const float4 h = *(const float4*)(hk + r * 96);
            FMA4(acc[r], h, w0, w1, w2, w3);
        }
    }

    float sq[32];
    const float* ep = eps + r0 * P + j0;
    float* sp = out_sample + r0 * P + j0;
    #pragma unroll
    for (int r = 0; r < 32; ++r) {
        const float m0 = 1.f / (1.f + __expf(-acc[r].x));
        const float m1 = 1.f / (1.f + __expf(-acc[r].y));
        const float m2 = 1.f / (1.f + __expf(-acc[r].z));
        const float m3 = 1.f / (1.f + __expf(-acc[r].w));
        const float4 e = *(const float4*)(ep + r * P);
        const float s0 = fminf(fmaxf(fmaf(0.22360679774997896f, e.x, m0), 0.f), 1.f);
        const float s1 = fminf(fmaxf(fmaf(0.22360679774997896f, e.y, m1), 0.f), 1.f);
        const float s2 = fminf(fmaxf(fmaf(0.22360679774997896f, e.z, m2), 0.f), 1.f);
        const float s3 = fminf(fmaxf(fmaf(0.22360679774997896f, e.w, m3), 0.f), 1.f);
        *(float4*)(sp + r * P) = make_float4(s0, s1, s2, s3);
        const float d0 = s0 - m0, d1 = s1 - m1, d2 = s2 - m2, d3 = s3 - m3;
        sq[r] = fmaf(d0, d0, fmaf(d1, d1, fmaf(d2, d2, d3 * d3)));
    }
    #pragma unroll
    for (int r = 0; r < 32; ++r) {
        float v = sq[r];
        v += __shfl_xor(v, 1);
        v += __shfl_xor(v, 2);
        v += __shfl_xor(v, 4);
        v += __shfl_xor(v, 8);
        v += __shfl_xor(v, 16);
        v += __shfl_xor(v, 32);
        if ((t & 63) == 0) s_red[r][t >> 6] = v;
    }
    __syncthreads();
    if (t < 32) {
        const float v = s_red[t][0] + s_red[t][1] + s_red[t][2] + s_red[t][3];
        out_logprob[r0 + t] = fmaf(-10.f, v, 592.8218660580586f);
        out_entropy[r0 + t] = -80.82186605805855f;
    }
}

extern "C" void kernel_launch(void* const* d_in, const int* in_sizes, int n_in,
                              void* d_out, int out_size, void* d_ws, size_t ws_size,
                              hipStream_t stream) {
    const float* encoding = (const float*)d_in[0];
    const float* mean     = (const float*)d_in[1];
    const float* enc_w1   = (const float*)d_in[2];
    const float* enc_w2   = (const float*)d_in[3];
    const float* pol_w1   = (const float*)d_in[4];
    const float* pol_b1   = (const float*)d_in[5];
    const float* pol_w2   = (const float*)d_in[6];
    const float* pol_b2   = (const float*)d_in[7];
    const float* pol_w3   = (const float*)d_in[8];
    const float* pol_b3   = (const float*)d_in[9];
    const float* comb_w   = (const float*)d_in[10];
    const float* comb_b   = (const float*)d_in[11];
    const float* eps      = (const float*)d_in[12];

    float* fused = (float*)d_ws;                          // 97*1024 floats
    float* h1h2  = fused + 97 * 1024;                     // 16384*96 floats
    float* out_sample  = (float*)d_out;
    float* out_logprob = out_sample + (size_t)N_CLIENTS * P;
    float* out_entropy = out_logprob + N_CLIENTS;

    (void)hipMemsetAsync(fused, 0, 97 * 1024 * sizeof(float), stream);

    stage1<<<1600, 256, 0, stream>>>(encoding, mean, enc_w1, pol_w1, pol_b1,
                                     pol_w2, pol_b2, enc_w2, pol_w3, pol_b3,
                                     comb_w, comb_b, h1h2, fused);

    logits_ep<<<N_CLIENTS / 32, 256, 0, stream>>>(
        h1h2, fused, eps, out_sample, out_logprob, out_entropy);
}